// Round 1
// baseline (371.752 us; speedup 1.0000x reference)
//
#include <hip/hip_runtime.h>
#include <hip/hip_bf16.h>

// RBF kernel: out[n,m] = exp(-max(||x_n||^2 + ||p_m||^2 - 2 x.p, 0)), gamma=1.
// N=131072, M=512, D=64, fp32.
// Block = 256 threads (4 waves), covers 128 x-rows x full M (4 chunks of 128 m).
// Tiles staged d-major (transposed) in LDS so GEMM reads are ds_read_b128:
//   xT[d][n]: read float4 over n (broadcast x-scalars), pT[d][m]: float4 over m.
// Per-thread register tile 8n x 8m (acc = 8 x 2 float4, vectorized over m so
// stores are coalesced dwordx4).

#define N_PTS 131072
#define M_PROT 512
#define D_DIM 64
#define BN 128
#define BM 128
#define NCHUNK (M_PROT / BM)

#define FMA4(a, s, v)                \
  {                                  \
    (a).x = fmaf((s), (v).x, (a).x); \
    (a).y = fmaf((s), (v).y, (a).y); \
    (a).z = fmaf((s), (v).z, (a).z); \
    (a).w = fmaf((s), (v).w, (a).w); \
  }

__global__ __launch_bounds__(256, 2)
void rbf_kernel(const float* __restrict__ x,
                const float* __restrict__ prot,
                float* __restrict__ out) {
  __shared__ float xT[D_DIM][BN];  // 32 KiB, x tile transposed: xT[d][r] = x[n0+r][d]
  __shared__ float pT[D_DIM][BM];  // 32 KiB, p chunk transposed
  __shared__ float xs[BN];         // ||x_n||^2
  __shared__ float ps[BM];         // ||p_m||^2 (per chunk)

  const int tid = threadIdx.x;
  const int tx = tid & 15;   // m-thread: m = mc*128 + g*64 + tx*4 + c
  const int ty = tid >> 4;   // n-thread: n = n0 + ty*8 + i
  const int n0 = blockIdx.x * BN;

  // ---- stage x tile, transposed (once per block) ----
#pragma unroll
  for (int i = 0; i < 8; ++i) {
    const int idx = tid + i * 256;     // 0..2047
    const int r  = idx >> 4;           // row 0..127
    const int c4 = idx & 15;           // float4-col 0..15
    const float4 v = *reinterpret_cast<const float4*>(x + (size_t)(n0 + r) * D_DIM + c4 * 4);
    xT[c4 * 4 + 0][r] = v.x;
    xT[c4 * 4 + 1][r] = v.y;
    xT[c4 * 4 + 2][r] = v.z;
    xT[c4 * 4 + 3][r] = v.w;
  }

  for (int mc = 0; mc < NCHUNK; ++mc) {
    // ---- stage p chunk, transposed ----
    // Safe without a leading barrier: previous chunk's GEMM (the only pT
    // reader) finished before the post-GEMM barrier of the previous iter.
#pragma unroll
    for (int i = 0; i < 8; ++i) {
      const int idx = tid + i * 256;
      const int r  = idx >> 4;
      const int c4 = idx & 15;
      const float4 v =
          *reinterpret_cast<const float4*>(prot + (size_t)(mc * BM + r) * D_DIM + c4 * 4);
      pT[c4 * 4 + 0][r] = v.x;
      pT[c4 * 4 + 1][r] = v.y;
      pT[c4 * 4 + 2][r] = v.z;
      pT[c4 * 4 + 3][r] = v.w;
    }
    __syncthreads();  // B1: tiles visible

    // ---- norms from LDS (visible to readers at B2) ----
    if (mc == 0 && tid < BN) {
      float s = 0.f;
#pragma unroll 8
      for (int d = 0; d < D_DIM; ++d) {
        const float v = xT[d][tid];
        s = fmaf(v, v, s);
      }
      xs[tid] = s;
    }
    if (tid >= 128) {
      const int m = tid - 128;
      float s = 0.f;
#pragma unroll 8
      for (int d = 0; d < D_DIM; ++d) {
        const float v = pT[d][m];
        s = fmaf(v, v, s);
      }
      ps[m] = s;
    }

    // ---- GEMM: acc[i][g] = sum_d x[n_i][d] * p[m_g][d], m-vectorized ----
    float4 acc[8][2];
#pragma unroll
    for (int i = 0; i < 8; ++i) {
      acc[i][0] = make_float4(0.f, 0.f, 0.f, 0.f);
      acc[i][1] = make_float4(0.f, 0.f, 0.f, 0.f);
    }

#pragma unroll 4
    for (int d = 0; d < D_DIM; ++d) {
      const float4 xa = *reinterpret_cast<const float4*>(&xT[d][ty * 8]);
      const float4 xb = *reinterpret_cast<const float4*>(&xT[d][ty * 8 + 4]);
      const float4 p0 = *reinterpret_cast<const float4*>(&pT[d][tx * 4]);
      const float4 p1 = *reinterpret_cast<const float4*>(&pT[d][64 + tx * 4]);
      const float xsc[8] = {xa.x, xa.y, xa.z, xa.w, xb.x, xb.y, xb.z, xb.w};
#pragma unroll
      for (int i = 0; i < 8; ++i) {
        FMA4(acc[i][0], xsc[i], p0);
        FMA4(acc[i][1], xsc[i], p1);
      }
    }
    __syncthreads();  // B2: GEMM LDS reads done; norm writes visible

    // ---- epilogue: exp(min(2*dot - xs - ps, 0)), coalesced f4 stores ----
    const int mbase = mc * BM;
#pragma unroll
    for (int i = 0; i < 8; ++i) {
      const int n = n0 + ty * 8 + i;
      const float xsn = xs[ty * 8 + i];
#pragma unroll
      for (int g = 0; g < 2; ++g) {
        const float4 psv = *reinterpret_cast<const float4*>(&ps[g * 64 + tx * 4]);
        const float4 a = acc[i][g];
        float4 r;
        r.x = __expf(fminf(fmaf(2.f, a.x, -xsn) - psv.x, 0.f));
        r.y = __expf(fminf(fmaf(2.f, a.y, -xsn) - psv.y, 0.f));
        r.z = __expf(fminf(fmaf(2.f, a.z, -xsn) - psv.z, 0.f));
        r.w = __expf(fminf(fmaf(2.f, a.w, -xsn) - psv.w, 0.f));
        *reinterpret_cast<float4*>(out + (size_t)n * M_PROT + mbase + g * 64 + tx * 4) = r;
      }
    }
  }
}

extern "C" void kernel_launch(void* const* d_in, const int* in_sizes, int n_in,
                              void* d_out, int out_size, void* d_ws, size_t ws_size,
                              hipStream_t stream) {
  const float* x = (const float*)d_in[0];
  const float* p = (const float*)d_in[1];
  float* out = (float*)d_out;
  (void)in_sizes; (void)n_in; (void)out_size; (void)d_ws; (void)ws_size;
  rbf_kernel<<<N_PTS / BN, 256, 0, stream>>>(x, p, out);
}

// Round 5
// 342.701 us; speedup vs baseline: 1.0848x; 1.0848x over previous
//
#include <hip/hip_runtime.h>
#include <hip/hip_bf16.h>

// RBF kernel out[n,m] = exp(-max(||x_n||^2 + ||p_m||^2 - 2 x.p, 0)), gamma=1.
// N=131072, M=512, D=64, fp32 in/out.
//
// MFMA path: split x = xh + xl, p = ph + pl (bf16 + bf16 residual).
// cross = xh.ph + xh.pl + xl.ph  (xl.pl dropped, ~1e-5 abs error in dist2).
// => K=192 bf16 GEMM via v_mfma_f32_16x16x32_bf16. Norms exact fp32.
//
// Block: 256 thr (4 waves), tile 128n x 128m. Wave quadrant 64x64 = 4x4 frags.
// LDS tiles padded to 72 bf16/row (144 B): b128 frag reads are 2-way = free.

#define N_PTS 131072
#define M_PROT 512
#define D_DIM 64
#define BN 128
#define BM 128
#define LDP 72  // padded row stride (bf16 elems); 144 B, multiple of 16 B

typedef __attribute__((ext_vector_type(8))) short short8;
typedef __attribute__((ext_vector_type(4))) float f32x4;

__device__ inline ushort f2bf(float f) {
  uint u = __float_as_uint(f);
  uint r = (u + 0x7FFFu + ((u >> 16) & 1u)) >> 16;
  return (ushort)r;
}
__device__ inline float bf2f(ushort h) { return __uint_as_float(((uint)h) << 16); }

__device__ inline void split4(float4 v, uint2& hp, uint2& lp) {
  ushort h0 = f2bf(v.x), h1 = f2bf(v.y), h2 = f2bf(v.z), h3 = f2bf(v.w);
  ushort l0 = f2bf(v.x - bf2f(h0));
  ushort l1 = f2bf(v.y - bf2f(h1));
  ushort l2 = f2bf(v.z - bf2f(h2));
  ushort l3 = f2bf(v.w - bf2f(h3));
  hp.x = (uint)h0 | ((uint)h1 << 16);
  hp.y = (uint)h2 | ((uint)h3 << 16);
  lp.x = (uint)l0 | ((uint)l1 << 16);
  lp.y = (uint)l2 | ((uint)l3 << 16);
}

__global__ __launch_bounds__(256, 2)
void rbf_mfma(const float* __restrict__ x,
              const float* __restrict__ prot,
              float* __restrict__ out) {
  __shared__ ushort XH[BN][LDP], XL[BN][LDP];
  __shared__ ushort PH[BM][LDP], PL[BM][LDP];
  __shared__ float XS[BN], PS[BM];

  const int tid = threadIdx.x;
  const int bid = blockIdx.x;
  const int n0 = (bid >> 2) * BN;   // m fastest: 4 m-tiles share one x-tile
  const int m0 = (bid & 3) * BM;

  // ---- stage + hi/lo-split x tile and p tile into LDS ----
#pragma unroll
  for (int i = 0; i < 8; ++i) {
    const int idx = tid + i * 256;  // 0..2047
    const int r = idx >> 4;
    const int c4 = idx & 15;
    const float4 v = *reinterpret_cast<const float4*>(x + (size_t)(n0 + r) * D_DIM + c4 * 4);
    uint2 hp, lp;
    split4(v, hp, lp);
    *reinterpret_cast<uint2*>(&XH[r][c4 * 4]) = hp;
    *reinterpret_cast<uint2*>(&XL[r][c4 * 4]) = lp;
  }
#pragma unroll
  for (int i = 0; i < 8; ++i) {
    const int idx = tid + i * 256;
    const int r = idx >> 4;
    const int c4 = idx & 15;
    const float4 v = *reinterpret_cast<const float4*>(prot + (size_t)(m0 + r) * D_DIM + c4 * 4);
    uint2 hp, lp;
    split4(v, hp, lp);
    *reinterpret_cast<uint2*>(&PH[r][c4 * 4]) = hp;
    *reinterpret_cast<uint2*>(&PL[r][c4 * 4]) = lp;
  }

  // ---- exact fp32 norms from global (L1/L2-hot re-read) ----
  {
    const int r = tid & 127;
    const float* src = (tid < 128) ? (x + (size_t)(n0 + r) * D_DIM)
                                   : (prot + (size_t)(m0 + r) * D_DIM);
    float s = 0.f;
#pragma unroll
    for (int c = 0; c < 16; ++c) {
      const float4 v = *reinterpret_cast<const float4*>(src + c * 4);
      s = fmaf(v.x, v.x, s);
      s = fmaf(v.y, v.y, s);
      s = fmaf(v.z, v.z, s);
      s = fmaf(v.w, v.w, s);
    }
    if (tid < 128) XS[r] = s; else PS[r] = s;
  }
  __syncthreads();

  // ---- MFMA: wave (wr,wc) owns 64x64 quadrant; 4x4 frags of 16x16 ----
  const int lane = tid & 63;
  const int wave = tid >> 6;
  const int wr = wave >> 1, wc = wave & 1;
  const int lrow = lane & 15;          // A-row / B-col within frag
  const int kg16 = (lane >> 4) * 8;    // k-subgroup d-offset

  f32x4 acc[4][4];
#pragma unroll
  for (int i = 0; i < 4; ++i)
#pragma unroll
    for (int j = 0; j < 4; ++j)
      acc[i][j] = (f32x4){0.f, 0.f, 0.f, 0.f};

#pragma unroll
  for (int s = 0; s < 3; ++s) {
    const ushort(*A)[LDP] = (s == 2) ? XL : XH;
    const ushort(*B)[LDP] = (s == 1) ? PL : PH;
#pragma unroll
    for (int h = 0; h < 2; ++h) {
      const int d0 = h * 32 + kg16;
      short8 a[4], b[4];
#pragma unroll
      for (int f = 0; f < 4; ++f) {
        a[f] = *reinterpret_cast<const short8*>(&A[wr * 64 + f * 16 + lrow][d0]);
        b[f] = *reinterpret_cast<const short8*>(&B[wc * 64 + f * 16 + lrow][d0]);
      }
#pragma unroll
      for (int i = 0; i < 4; ++i)
#pragma unroll
        for (int j = 0; j < 4; ++j)
          acc[i][j] = __builtin_amdgcn_mfma_f32_16x16x32_bf16(a[i], b[j], acc[i][j], 0, 0, 0);
      }
  }

  // ---- epilogue: out = exp(min(2c - xs - ps, 0)) ----
  // C/D layout (HW-verified): col = lane&15, row = (lane>>4)*4 + reg.
  const int rloc = wr * 64 + (lane >> 4) * 4;  // + i*16 + reg
  const int cloc = wc * 64 + (lane & 15);      // + j*16
#pragma unroll
  for (int i = 0; i < 4; ++i) {
#pragma unroll
    for (int j = 0; j < 4; ++j) {
      const f32x4 c = acc[i][j];
      const int col = cloc + j * 16;
      const float psv = PS[col];
      float* outp = out + (size_t)(n0 + rloc + i * 16) * M_PROT + (m0 + col);
#pragma unroll
      for (int r = 0; r < 4; ++r) {
        const float xsv = XS[rloc + i * 16 + r];
        const float e = fminf(fmaf(2.f, c[r], -xsv) - psv, 0.f);
        outp[(size_t)r * M_PROT] = __expf(e);
      }
    }
  }
}

extern "C" void kernel_launch(void* const* d_in, const int* in_sizes, int n_in,
                              void* d_out, int out_size, void* d_ws, size_t ws_size,
                              hipStream_t stream) {
  const float* x = (const float*)d_in[0];
  const float* p = (const float*)d_in[1];
  float* out = (float*)d_out;
  (void)in_sizes; (void)n_in; (void)out_size; (void)d_ws; (void)ws_size;
  rbf_mfma<<<dim3((N_PTS / BN) * (M_PROT / BM)), 256, 0, stream>>>(x, p, out);
}